// Round 2
// baseline (6195.575 us; speedup 1.0000x reference)
//
#include <hip/hip_runtime.h>
#include <cstdint>
#include <cstddef>

// ---------------------------------------------------------------------------
// RNN_42537356100303: 3-layer tanh RNN (B=128,T=1024,F=24,H=512) + MLP head.
// Phase plan (all on one in-place f16 buffer P[B*T, 512] in ws):
//   k_cvt   : fp32 weights -> f16 (W_hh0..2, W_ih1..2), bias_l = b_ih+b_hh
//   k_xp0   : P = x @ W_ih0^T + bias0            (VALU, K=24)
//   k_scan  : P[b,t,:] = h_t  (in-place over xp), per-batch WG, W_hh resident
//             in VGPRs (384 cols) + LDS (128 cols)
//   k_proj  : P = P @ W_ih^T + bias  (in-place row-block MFMA f16 GEMM)
//   k_head  : out = silu(last @ W1^T + b1) @ W2^T + b2
// ---------------------------------------------------------------------------

typedef _Float16 half_t;
typedef __attribute__((ext_vector_type(2))) _Float16 half2_t;
typedef __attribute__((ext_vector_type(8))) _Float16 frag8;
typedef __attribute__((ext_vector_type(4))) float    frag4;

union U32H2 { unsigned u; half2_t h2; };

__device__ __forceinline__ float dot2(unsigned a, unsigned b, float c) {
#if __has_builtin(__builtin_amdgcn_fdot2)
    U32H2 ua; ua.u = a; U32H2 ub; ub.u = b;
    return __builtin_amdgcn_fdot2(ua.h2, ub.h2, c, false);
#else
    U32H2 ua; ua.u = a; U32H2 ub; ub.u = b;
    c += (float)ua.h2.x * (float)ub.h2.x;
    c += (float)ua.h2.y * (float)ub.h2.y;
    return c;
#endif
}

__device__ __forceinline__ float fast_tanh(float x) {
    float ax = __builtin_fabsf(x);
    float e  = __expf(-2.f * ax);          // v_exp_f32 path
    float r  = (1.f - e) / (1.f + e);
    return __builtin_copysignf(r, x);
}

#define WN (512 * 512)

// -------------------------------------------------------------- k_cvt ------
__global__ __launch_bounds__(256) void k_cvt(
    const float* whh0, const float* whh1, const float* whh2,
    const float* wih1, const float* wih2,
    const float* bi0, const float* bh0, const float* bi1, const float* bh1,
    const float* bi2, const float* bh2,
    half_t* w16, float* bias)
{
    int idx = blockIdx.x * 256 + threadIdx.x;
    if (idx < 5 * WN) {
        int seg = idx / WN, off = idx % WN;
        const float* s = seg == 0 ? whh0 : seg == 1 ? whh1 : seg == 2 ? whh2
                       : seg == 3 ? wih1 : wih2;
        w16[idx] = (half_t)s[off];
    } else {
        int j = idx - 5 * WN;
        if (j < 3 * 512) {
            int l = j >> 9, o = j & 511;
            const float* a = l == 0 ? bi0 : l == 1 ? bi1 : bi2;
            const float* c = l == 0 ? bh0 : l == 1 ? bh1 : bh2;
            bias[j] = a[o] + c[o];
        }
    }
}

// -------------------------------------------------------------- k_xp0 ------
// 32 rows/block. r = tid>>3 (row), c = tid&7 (o-octet within row) so that 8
// consecutive lanes store 8 contiguous uint4 (128 B) within one P row.
__global__ __launch_bounds__(256) void k_xp0(
    const float* __restrict__ x, const float* __restrict__ wih0,
    const float* __restrict__ bias0, half_t* __restrict__ P)
{
    __shared__ float wl[512 * 24];
    __shared__ float xl[32 * 25];
    int tid = threadIdx.x;
    int r0  = blockIdx.x * 32;
    for (int i = tid; i < 512 * 24; i += 256) wl[i] = wih0[i];
    for (int i = tid; i < 32 * 24; i += 256) {       // FIXED: full coverage
        int r = i / 24, f = i % 24;
        xl[r * 25 + f] = x[(size_t)(r0 + r) * 24 + f];
    }
    __syncthreads();
    int r = tid >> 3, c = tid & 7;
    float xr[24];
#pragma unroll
    for (int f = 0; f < 24; f++) xr[f] = xl[r * 25 + f];
    size_t orow = (size_t)(r0 + r) * 512;
    for (int og = 0; og < 8; og++) {
        half_t hv[8];
#pragma unroll
        for (int oj = 0; oj < 8; oj++) {
            int o = og * 64 + c * 8 + oj;
            float acc = bias0[o];
#pragma unroll
            for (int f = 0; f < 24; f++) acc = fmaf(xr[f], wl[o * 24 + f], acc);
            hv[oj] = (half_t)acc;
        }
        *(uint4*)(P + orow + og * 64 + c * 8) = *(const uint4*)hv;
    }
}

// -------------------------------------------------------------- k_scan -----
// One WG (512 thr) per batch element. Thread o owns output row o of W_hh:
//   k in [0,384) in VGPRs (48 uint4 = 192 regs of packed f16 pairs)
//   k in [384,512) in LDS, column-major by u32 pair: wlds[j*512 + o]
// h double-buffered in LDS as packed f16; 1 barrier/step.
__global__ __launch_bounds__(512, 2) void k_scan(
    half_t* __restrict__ P, const half_t* __restrict__ whh)
{
    extern __shared__ char smem[];
    unsigned* wlds = (unsigned*)smem;               // [64][512] u32  (128 KB)
    unsigned* hbuf = (unsigned*)(smem + 131072);    // [2][256] u32  (2 KB)

    int o = threadIdx.x;
    int b = blockIdx.x;

    const uint4* wrow = (const uint4*)(whh + (size_t)o * 512);  // 64 uint4/row
    uint4 wreg[48];
#pragma unroll
    for (int g = 0; g < 48; g++) wreg[g] = wrow[g];
#pragma unroll
    for (int g = 0; g < 16; g++) {                  // k-pairs 192..255 -> LDS
        uint4 v = wrow[48 + g];
        wlds[(g * 4 + 0) * 512 + o] = v.x;
        wlds[(g * 4 + 1) * 512 + o] = v.y;
        wlds[(g * 4 + 2) * 512 + o] = v.z;
        wlds[(g * 4 + 3) * 512 + o] = v.w;
    }
    if (o < 256) { hbuf[o] = 0u; hbuf[256 + o] = 0u; }   // h0 = 0
    __syncthreads();

    half_t* Pb = P + (size_t)b * 1024 * 512;
    int cur = 0;
    float xp_next = (float)Pb[o];                   // t = 0 prefetch
    for (int t = 0; t < 1024; t++) {
        float acc0 = xp_next, acc1 = 0.f, acc2 = 0.f, acc3 = 0.f;
        int tn = t + 1 < 1024 ? t + 1 : 1023;
        xp_next = (float)Pb[(size_t)tn * 512 + o];  // prefetch next xp

        const uint4* h4 = (const uint4*)(hbuf + cur * 256);
#pragma unroll
        for (int g = 0; g < 48; g++) {              // register part k<384
            uint4 hv = h4[g];
            uint4 wv = wreg[g];
            acc0 = dot2(wv.x, hv.x, acc0);
            acc1 = dot2(wv.y, hv.y, acc1);
            acc2 = dot2(wv.z, hv.z, acc2);
            acc3 = dot2(wv.w, hv.w, acc3);
        }
#pragma unroll
        for (int g = 0; g < 16; g++) {              // LDS part k in [384,512)
            uint4 hv = h4[48 + g];
            acc0 = dot2(wlds[(g * 4 + 0) * 512 + o], hv.x, acc0);
            acc1 = dot2(wlds[(g * 4 + 1) * 512 + o], hv.y, acc1);
            acc2 = dot2(wlds[(g * 4 + 2) * 512 + o], hv.z, acc2);
            acc3 = dot2(wlds[(g * 4 + 3) * 512 + o], hv.w, acc3);
        }
        float hn = fast_tanh((acc0 + acc1) + (acc2 + acc3));
        half_t hh = (half_t)hn;
        ((half_t*)(hbuf + (cur ^ 1) * 256))[o] = hh;
        Pb[(size_t)t * 512 + o] = hh;               // in-place over xp
        __syncthreads();
        cur ^= 1;
    }
}

// -------------------------------------------------------------- k_proj -----
// In-place row-block GEMM: rows [r0, r0+64) of P times W^T (W = [512 o][512 k]
// f16), + bias, overwrite. MFMA f32_16x16x32_f16.
// A frag: A[m=lane&15][k = kb*32 + (lane>>4)*8 + j]   (m120-verified pattern)
// B frag: B[k][n=lane&15], same k mapping. C/D: col=lane&15,row=(lane>>4)*4+i.
__global__ __launch_bounds__(256, 2) void k_proj(
    half_t* __restrict__ P, const half_t* __restrict__ w16,
    const float* __restrict__ bias)
{
    extern __shared__ char smem[];
    half_t* A = (half_t*)smem;                  // 64 rows x stride 520 (65 KB)
    const int AS = 520;
    int tid = threadIdx.x;
    size_t r0 = (size_t)blockIdx.x * 64;

    const uint4* Pg = (const uint4*)(P + r0 * 512);
    for (int u = tid; u < 4096; u += 256) {     // 64 rows x 64 uint4
        uint4 v = Pg[u];
        int row = u >> 6, col = u & 63;
        *(uint4*)(A + row * AS + col * 8) = v;
    }
    __syncthreads();

    int wave = tid >> 6, lane = tid & 63;
    int lm = lane & 15, lq = lane >> 4;

    frag4 acc[4][8];
#pragma unroll
    for (int mt = 0; mt < 4; mt++)
#pragma unroll
        for (int nt = 0; nt < 8; nt++) acc[mt][nt] = (frag4){0.f, 0.f, 0.f, 0.f};

    for (int kb = 0; kb < 16; kb++) {
        int k0 = kb * 32 + lq * 8;
        frag8 af[4];
#pragma unroll
        for (int mt = 0; mt < 4; mt++)
            af[mt] = *(const frag8*)(A + (mt * 16 + lm) * AS + k0);
        frag8 bf[8];
#pragma unroll
        for (int nt = 0; nt < 8; nt++) {
            int n = wave * 128 + nt * 16 + lm;
            bf[nt] = *(const frag8*)(w16 + (size_t)n * 512 + k0);
        }
#pragma unroll
        for (int mt = 0; mt < 4; mt++)
#pragma unroll
            for (int nt = 0; nt < 8; nt++)
                acc[mt][nt] = __builtin_amdgcn_mfma_f32_16x16x32_f16(
                    af[mt], bf[nt], acc[mt][nt], 0, 0, 0);
    }

#pragma unroll
    for (int mt = 0; mt < 4; mt++) {
        int row = mt * 16 + lq * 4;
#pragma unroll
        for (int nt = 0; nt < 8; nt++) {
            int oc = wave * 128 + nt * 16 + lm;
            float bo = bias[oc];
#pragma unroll
            for (int i = 0; i < 4; i++) {
                float v = acc[mt][nt][i] + bo;
                P[(r0 + row + i) * 512 + oc] = (half_t)v;
            }
        }
    }
}

// -------------------------------------------------------------- k_head -----
__global__ __launch_bounds__(256) void k_head(
    const half_t* __restrict__ P, const float* __restrict__ W1,
    const float* __restrict__ b1, const float* __restrict__ W2,
    const float* __restrict__ b2, float* __restrict__ out)
{
    __shared__ float lastv[512];
    __shared__ float zl[1024];
    __shared__ float red[8][33];
    int tid = threadIdx.x, b = blockIdx.x;
    const half_t* lr = P + ((size_t)b * 1024 + 1023) * 512;
    lastv[tid]       = (float)lr[tid];
    lastv[tid + 256] = (float)lr[tid + 256];
    __syncthreads();
#pragma unroll
    for (int i = 0; i < 4; i++) {
        int m = tid + 256 * i;
        const float* wr = W1 + (size_t)m * 512;
        float acc = b1[m];
        for (int k = 0; k < 512; k += 4) {
            float4 wv = *(const float4*)(wr + k);
            acc = fmaf(wv.x, lastv[k],     acc);
            acc = fmaf(wv.y, lastv[k + 1], acc);
            acc = fmaf(wv.z, lastv[k + 2], acc);
            acc = fmaf(wv.w, lastv[k + 3], acc);
        }
        zl[m] = acc / (1.f + __expf(-acc));         // silu
    }
    __syncthreads();
    int c = tid & 7, mc = tid >> 3;                 // 8 outputs x 32 m-chunks
    float p = 0.f;
#pragma unroll
    for (int j = 0; j < 32; j++) {
        int m = mc * 32 + j;
        p = fmaf(zl[m], W2[c * 1024 + m], p);
    }
    red[c][mc] = p;
    __syncthreads();
    if (tid < 8) {
        float s = b2[tid];
#pragma unroll
        for (int j = 0; j < 32; j++) s += red[tid][j];
        out[b * 8 + tid] = s;
    }
}

// ---------------------------------------------------------------------------
extern "C" void kernel_launch(void* const* d_in, const int* in_sizes, int n_in,
                              void* d_out, int out_size, void* d_ws, size_t ws_size,
                              hipStream_t stream)
{
    const float* x    = (const float*)d_in[0];
    const float* wih0 = (const float*)d_in[1];
    const float* whh0 = (const float*)d_in[2];
    const float* bi0  = (const float*)d_in[3];
    const float* bh0  = (const float*)d_in[4];
    const float* wih1 = (const float*)d_in[5];
    const float* whh1 = (const float*)d_in[6];
    const float* bi1  = (const float*)d_in[7];
    const float* bh1  = (const float*)d_in[8];
    const float* wih2 = (const float*)d_in[9];
    const float* whh2 = (const float*)d_in[10];
    const float* bi2  = (const float*)d_in[11];
    const float* bh2  = (const float*)d_in[12];
    const float* W1   = (const float*)d_in[13];
    const float* b1   = (const float*)d_in[14];
    const float* W2   = (const float*)d_in[15];
    const float* b2   = (const float*)d_in[16];
    float* out = (float*)d_out;

    char* ws = (char*)d_ws;
    half_t* P    = (half_t*)ws;                               // 134,217,728 B
    half_t* W16  = (half_t*)(ws + 134217728);                 //   2,621,440 B
    float*  bias = (float*)(ws + 134217728 + 2621440);        //       6,144 B

    // dynamic-LDS opt-in (>64 KB); idempotent, not a stream op
    hipFuncSetAttribute((const void*)k_scan,
                        hipFuncAttributeMaxDynamicSharedMemorySize, 133120);
    hipFuncSetAttribute((const void*)k_proj,
                        hipFuncAttributeMaxDynamicSharedMemorySize, 66560);

    k_cvt<<<5126, 256, 0, stream>>>(whh0, whh1, whh2, wih1, wih2,
                                    bi0, bh0, bi1, bh1, bi2, bh2, W16, bias);
    k_xp0<<<4096, 256, 0, stream>>>(x, wih0, bias, P);
    k_scan<<<128, 512, 133120, stream>>>(P, W16 + 0 * WN);
    k_proj<<<2048, 256, 66560, stream>>>(P, W16 + 3 * WN, bias + 512);
    k_scan<<<128, 512, 133120, stream>>>(P, W16 + 1 * WN);
    k_proj<<<2048, 256, 66560, stream>>>(P, W16 + 4 * WN, bias + 1024);
    k_scan<<<128, 512, 133120, stream>>>(P, W16 + 2 * WN);
    k_head<<<128, 256, 0, stream>>>(P, W1, b1, W2, b2, out);
}

// Round 3
// 5574.743 us; speedup vs baseline: 1.1114x; 1.1114x over previous
//
#include <hip/hip_runtime.h>
#include <cstdint>
#include <cstddef>

// ---------------------------------------------------------------------------
// RNN_42537356100303: 3-layer tanh RNN (B=128,T=1024,F=24,H=512) + MLP head.
// Phase plan (all on one in-place f16 buffer P[B*T, 512] in ws):
//   k_cvt   : fp32 weights -> f16 (W_hh0..2, W_ih1..2), bias_l = b_ih+b_hh
//   k_xp0   : P = x @ W_ih0^T + bias0            (VALU, K=24)
//   k_scan  : P[b,t,:] = h_t  (in-place over xp), per-batch WG, W_hh resident
//             in regs (448 cols) + LDS (64 cols, swizzled b128)
//   k_proj  : P = P @ W_ih^T + bias  (in-place row-block MFMA f16 GEMM)
//   k_head  : out = silu(last @ W1^T + b1) @ W2^T + b2
// ---------------------------------------------------------------------------

typedef _Float16 half_t;
typedef __attribute__((ext_vector_type(2))) _Float16 half2_t;
typedef __attribute__((ext_vector_type(8))) _Float16 frag8;
typedef __attribute__((ext_vector_type(4))) float    frag4;

union U32H2 { unsigned u; half2_t h2; };

__device__ __forceinline__ float dot2(unsigned a, unsigned b, float c) {
#if __has_builtin(__builtin_amdgcn_fdot2)
    U32H2 ua; ua.u = a; U32H2 ub; ub.u = b;
    return __builtin_amdgcn_fdot2(ua.h2, ub.h2, c, false);
#else
    U32H2 ua; ua.u = a; U32H2 ub; ub.u = b;
    c += (float)ua.h2.x * (float)ub.h2.x;
    c += (float)ua.h2.y * (float)ub.h2.y;
    return c;
#endif
}

__device__ __forceinline__ float fast_tanh(float x) {
    float ax = __builtin_fabsf(x);
    float e  = __expf(-2.f * ax);          // v_exp_f32 path
    float r  = (1.f - e) / (1.f + e);
    return __builtin_copysignf(r, x);
}

#define WN (512 * 512)

// -------------------------------------------------------------- k_cvt ------
__global__ __launch_bounds__(256) void k_cvt(
    const float* whh0, const float* whh1, const float* whh2,
    const float* wih1, const float* wih2,
    const float* bi0, const float* bh0, const float* bi1, const float* bh1,
    const float* bi2, const float* bh2,
    half_t* w16, float* bias)
{
    int idx = blockIdx.x * 256 + threadIdx.x;
    if (idx < 5 * WN) {
        int seg = idx / WN, off = idx % WN;
        const float* s = seg == 0 ? whh0 : seg == 1 ? whh1 : seg == 2 ? whh2
                       : seg == 3 ? wih1 : wih2;
        w16[idx] = (half_t)s[off];
    } else {
        int j = idx - 5 * WN;
        if (j < 3 * 512) {
            int l = j >> 9, o = j & 511;
            const float* a = l == 0 ? bi0 : l == 1 ? bi1 : bi2;
            const float* c = l == 0 ? bh0 : l == 1 ? bh1 : bh2;
            bias[j] = a[o] + c[o];
        }
    }
}

// -------------------------------------------------------------- k_xp0 ------
__global__ __launch_bounds__(256) void k_xp0(
    const float* __restrict__ x, const float* __restrict__ wih0,
    const float* __restrict__ bias0, half_t* __restrict__ P)
{
    __shared__ float wl[512 * 24];
    __shared__ float xl[32 * 25];
    int tid = threadIdx.x;
    int r0  = blockIdx.x * 32;
    for (int i = tid; i < 512 * 24; i += 256) wl[i] = wih0[i];
    for (int i = tid; i < 32 * 24; i += 256) {
        int r = i / 24, f = i % 24;
        xl[r * 25 + f] = x[(size_t)(r0 + r) * 24 + f];
    }
    __syncthreads();
    int r = tid >> 3, c = tid & 7;
    float xr[24];
#pragma unroll
    for (int f = 0; f < 24; f++) xr[f] = xl[r * 25 + f];
    size_t orow = (size_t)(r0 + r) * 512;
    for (int og = 0; og < 8; og++) {
        half_t hv[8];
#pragma unroll
        for (int oj = 0; oj < 8; oj++) {
            int o = og * 64 + c * 8 + oj;
            float acc = bias0[o];
#pragma unroll
            for (int f = 0; f < 24; f++) acc = fmaf(xr[f], wl[o * 24 + f], acc);
            hv[oj] = (half_t)acc;
        }
        *(uint4*)(P + orow + og * 64 + c * 8) = *(const uint4*)hv;
    }
}

// -------------------------------------------------------------- k_scan -----
// One WG (512 thr) per batch element. Thread o owns output row o of W_hh:
//   k in [0,448)   : 56 uint4 in registers (compiler may use AGPRs)
//   k in [448,512) : 8 uint4 in LDS, XOR-swizzled so the per-step reads are
//                    conflict-free ds_read_b128 (8 consecutive lanes cover
//                    all 32 banks).
// h double-buffered in LDS as packed f16 (b128 broadcast reads ~3cyc);
// 1 barrier/step.
__global__ __launch_bounds__(512, 2) void k_scan(
    half_t* __restrict__ P, const half_t* __restrict__ whh)
{
    extern __shared__ char smem[];
    uint4*    wl4  = (uint4*)smem;                  // [512*8] uint4 (64 KB)
    unsigned* hbuf = (unsigned*)(smem + 65536);     // [2][256] u32  (2 KB)

    int o = threadIdx.x;
    int b = blockIdx.x;
    int sw = o & 7;

    const uint4* wrow = (const uint4*)(whh + (size_t)o * 512);  // 64 uint4/row
    uint4 wreg[56];
#pragma unroll
    for (int g = 0; g < 56; g++) wreg[g] = wrow[g];
#pragma unroll
    for (int j = 0; j < 8; j++)                     // cols 448..511 -> LDS
        wl4[o * 8 + (j ^ sw)] = wrow[56 + j];
    if (o < 256) { hbuf[o] = 0u; hbuf[256 + o] = 0u; }   // h0 = 0
    __syncthreads();

    half_t* Pb = P + (size_t)b * 1024 * 512;
    int cur = 0;
    float xp_next = (float)Pb[o];                   // t = 0 prefetch
    for (int t = 0; t < 1024; t++) {
        float acc0 = xp_next, acc1 = 0.f, acc2 = 0.f, acc3 = 0.f;
        int tn = t + 1 < 1024 ? t + 1 : 1023;
        xp_next = (float)Pb[(size_t)tn * 512 + o];  // prefetch next xp

        const uint4* h4 = (const uint4*)(hbuf + cur * 256);
#pragma unroll
        for (int g = 0; g < 56; g++) {              // register part k<448
            uint4 hv = h4[g];
            uint4 wv = wreg[g];
            acc0 = dot2(wv.x, hv.x, acc0);
            acc1 = dot2(wv.y, hv.y, acc1);
            acc2 = dot2(wv.z, hv.z, acc2);
            acc3 = dot2(wv.w, hv.w, acc3);
        }
#pragma unroll
        for (int j = 0; j < 8; j++) {               // LDS part k in [448,512)
            uint4 hv = h4[56 + j];
            uint4 wv = wl4[o * 8 + (j ^ sw)];       // addr loop-invariant
            acc0 = dot2(wv.x, hv.x, acc0);
            acc1 = dot2(wv.y, hv.y, acc1);
            acc2 = dot2(wv.z, hv.z, acc2);
            acc3 = dot2(wv.w, hv.w, acc3);
        }
        float hn = fast_tanh((acc0 + acc1) + (acc2 + acc3));
        half_t hh = (half_t)hn;
        ((half_t*)(hbuf + (cur ^ 1) * 256))[o] = hh;
        Pb[(size_t)t * 512 + o] = hh;               // in-place over xp
        __syncthreads();
        cur ^= 1;
    }
}

// -------------------------------------------------------------- k_proj -----
// In-place row-block GEMM: rows [r0, r0+64) of P times W^T (W = [512 o][512 k]
// f16), + bias, overwrite. MFMA f32_16x16x32_f16.
__global__ __launch_bounds__(256, 2) void k_proj(
    half_t* __restrict__ P, const half_t* __restrict__ w16,
    const float* __restrict__ bias)
{
    extern __shared__ char smem[];
    half_t* A = (half_t*)smem;                  // 64 rows x stride 520 (65 KB)
    const int AS = 520;
    int tid = threadIdx.x;
    size_t r0 = (size_t)blockIdx.x * 64;

    const uint4* Pg = (const uint4*)(P + r0 * 512);
    for (int u = tid; u < 4096; u += 256) {     // 64 rows x 64 uint4
        uint4 v = Pg[u];
        int row = u >> 6, col = u & 63;
        *(uint4*)(A + row * AS + col * 8) = v;
    }
    __syncthreads();

    int wave = tid >> 6, lane = tid & 63;
    int lm = lane & 15, lq = lane >> 4;

    frag4 acc[4][8];
#pragma unroll
    for (int mt = 0; mt < 4; mt++)
#pragma unroll
        for (int nt = 0; nt < 8; nt++) acc[mt][nt] = (frag4){0.f, 0.f, 0.f, 0.f};

    for (int kb = 0; kb < 16; kb++) {
        int k0 = kb * 32 + lq * 8;
        frag8 af[4];
#pragma unroll
        for (int mt = 0; mt < 4; mt++)
            af[mt] = *(const frag8*)(A + (mt * 16 + lm) * AS + k0);
        frag8 bf[8];
#pragma unroll
        for (int nt = 0; nt < 8; nt++) {
            int n = wave * 128 + nt * 16 + lm;
            bf[nt] = *(const frag8*)(w16 + (size_t)n * 512 + k0);
        }
#pragma unroll
        for (int mt = 0; mt < 4; mt++)
#pragma unroll
            for (int nt = 0; nt < 8; nt++)
                acc[mt][nt] = __builtin_amdgcn_mfma_f32_16x16x32_f16(
                    af[mt], bf[nt], acc[mt][nt], 0, 0, 0);
    }

#pragma unroll
    for (int mt = 0; mt < 4; mt++) {
        int row = mt * 16 + lq * 4;
#pragma unroll
        for (int nt = 0; nt < 8; nt++) {
            int oc = wave * 128 + nt * 16 + lm;
            float bo = bias[oc];
#pragma unroll
            for (int i = 0; i < 4; i++) {
                float v = acc[mt][nt][i] + bo;
                P[(r0 + row + i) * 512 + oc] = (half_t)v;
            }
        }
    }
}

// -------------------------------------------------------------- k_head -----
__global__ __launch_bounds__(256) void k_head(
    const half_t* __restrict__ P, const float* __restrict__ W1,
    const float* __restrict__ b1, const float* __restrict__ W2,
    const float* __restrict__ b2, float* __restrict__ out)
{
    __shared__ float lastv[512];
    __shared__ float zl[1024];
    __shared__ float red[8][33];
    int tid = threadIdx.x, b = blockIdx.x;
    const half_t* lr = P + ((size_t)b * 1024 + 1023) * 512;
    lastv[tid]       = (float)lr[tid];
    lastv[tid + 256] = (float)lr[tid + 256];
    __syncthreads();
#pragma unroll
    for (int i = 0; i < 4; i++) {
        int m = tid + 256 * i;
        const float* wr = W1 + (size_t)m * 512;
        float acc = b1[m];
        for (int k = 0; k < 512; k += 4) {
            float4 wv = *(const float4*)(wr + k);
            acc = fmaf(wv.x, lastv[k],     acc);
            acc = fmaf(wv.y, lastv[k + 1], acc);
            acc = fmaf(wv.z, lastv[k + 2], acc);
            acc = fmaf(wv.w, lastv[k + 3], acc);
        }
        zl[m] = acc / (1.f + __expf(-acc));         // silu
    }
    __syncthreads();
    int c = tid & 7, mc = tid >> 3;                 // 8 outputs x 32 m-chunks
    float p = 0.f;
#pragma unroll
    for (int j = 0; j < 32; j++) {
        int m = mc * 32 + j;
        p = fmaf(zl[m], W2[c * 1024 + m], p);
    }
    red[c][mc] = p;
    __syncthreads();
    if (tid < 8) {
        float s = b2[tid];
#pragma unroll
        for (int j = 0; j < 32; j++) s += red[tid][j];
        out[b * 8 + tid] = s;
    }
}

// ---------------------------------------------------------------------------
extern "C" void kernel_launch(void* const* d_in, const int* in_sizes, int n_in,
                              void* d_out, int out_size, void* d_ws, size_t ws_size,
                              hipStream_t stream)
{
    const float* x    = (const float*)d_in[0];
    const float* wih0 = (const float*)d_in[1];
    const float* whh0 = (const float*)d_in[2];
    const float* bi0  = (const float*)d_in[3];
    const float* bh0  = (const float*)d_in[4];
    const float* wih1 = (const float*)d_in[5];
    const float* whh1 = (const float*)d_in[6];
    const float* bi1  = (const float*)d_in[7];
    const float* bh1  = (const float*)d_in[8];
    const float* wih2 = (const float*)d_in[9];
    const float* whh2 = (const float*)d_in[10];
    const float* bi2  = (const float*)d_in[11];
    const float* bh2  = (const float*)d_in[12];
    const float* W1   = (const float*)d_in[13];
    const float* b1   = (const float*)d_in[14];
    const float* W2   = (const float*)d_in[15];
    const float* b2   = (const float*)d_in[16];
    float* out = (float*)d_out;

    char* ws = (char*)d_ws;
    half_t* P    = (half_t*)ws;                               // 134,217,728 B
    half_t* W16  = (half_t*)(ws + 134217728);                 //   2,621,440 B
    float*  bias = (float*)(ws + 134217728 + 2621440);        //       6,144 B

    // dynamic-LDS opt-in (>64 KB); idempotent, not a stream op
    hipFuncSetAttribute((const void*)k_scan,
                        hipFuncAttributeMaxDynamicSharedMemorySize, 67584);
    hipFuncSetAttribute((const void*)k_proj,
                        hipFuncAttributeMaxDynamicSharedMemorySize, 66560);

    k_cvt<<<5126, 256, 0, stream>>>(whh0, whh1, whh2, wih1, wih2,
                                    bi0, bh0, bi1, bh1, bi2, bh2, W16, bias);
    k_xp0<<<4096, 256, 0, stream>>>(x, wih0, bias, P);
    k_scan<<<128, 512, 67584, stream>>>(P, W16 + 0 * WN);
    k_proj<<<2048, 256, 66560, stream>>>(P, W16 + 3 * WN, bias + 512);
    k_scan<<<128, 512, 67584, stream>>>(P, W16 + 1 * WN);
    k_proj<<<2048, 256, 66560, stream>>>(P, W16 + 4 * WN, bias + 1024);
    k_scan<<<128, 512, 67584, stream>>>(P, W16 + 2 * WN);
    k_head<<<128, 256, 0, stream>>>(P, W1, b1, W2, b2, out);
}